// Round 2
// baseline (582.899 us; speedup 1.0000x reference)
//
#include <hip/hip_runtime.h>

#define N_NODES 100000
#define N_EDGES 1250000
#define D_FEAT  64

// ---------------- superbin layout ----------------
#define SB_SHIFT 9
#define SB_NODES 512                                   // nodes per superbin
#define NSB      ((N_NODES + SB_NODES - 1) / SB_NODES) // 196
#define SBCAP    7168                                  // mean 6377 + ~10 sigma
#define OVF_CAP  32768

// ---------------- k1 ----------------
#define K1_THREADS 256
#define EPB        2048
#define EPT        (EPB / K1_THREADS)                  // 8
#define K1B        ((N_EDGES + EPB - 1) / EPB)         // 611

// ---------------- k23 ----------------
#define NPB   64                                       // nodes per gather block
#define NBLK  ((N_NODES + NPB - 1) / NPB)              // 1563
#define KCAP  1280                                     // kept-list cap (mean 800 + 17 sigma)

// ============ k1: superbin binning, 1-wave scan, run-coalesced writes ============
// 256 thr / 2048 edges: LDS hist over 196 bins -> single-wave shuffle scan
// (4 bins/lane, no barriers) -> LDS-staged local counting sort -> contiguous
// run writes (mean run ~10 words) into per-superbin slabs reserved with one
// global atomic per nonempty bin.
__global__ __launch_bounds__(K1_THREADS) void k1_bin_kernel(
        const int* __restrict__ idxi, const int* __restrict__ idxj,
        int* __restrict__ gcursor, int* __restrict__ ovfcnt,
        int* __restrict__ ovf, int* __restrict__ binbuf) {
    __shared__ int hist[NSB];
    __shared__ int runstart[NSB];
    __shared__ int gbase[NSB];
    __shared__ int cur[NSB];
    __shared__ int staged[EPB];                 // 8 KB
    __shared__ unsigned char sbin[EPB];         // 2 KB
    int t = threadIdx.x;
    if (t < NSB) hist[t] = 0;
    __syncthreads();

    int base = blockIdx.x * EPB;
    int n = N_EDGES - base; if (n > EPB) n = EPB;
    int d[EPT], s[EPT];
#pragma unroll
    for (int j = 0; j < EPT; ++j) {
        int i = t + j * K1_THREADS;
        if (i < n) {
            d[j] = idxi[base + i];
            s[j] = idxj[base + i];
            atomicAdd(&hist[d[j] >> SB_SHIFT], 1);
        } else {
            d[j] = -1;
        }
    }
    __syncthreads();

    // single-wave exclusive scan over 196 bins, 4 bins per lane, no barriers
    if (t < 64) {
        int b0 = 4 * t;
        int h0 = (b0     < NSB) ? hist[b0]     : 0;
        int h1 = (b0 + 1 < NSB) ? hist[b0 + 1] : 0;
        int h2 = (b0 + 2 < NSB) ? hist[b0 + 2] : 0;
        int h3 = (b0 + 3 < NSB) ? hist[b0 + 3] : 0;
        int s01 = h0 + h1;
        int sum = s01 + h2 + h3;
        int inc = sum;
#pragma unroll
        for (int off = 1; off < 64; off <<= 1) {
            int u = __shfl_up(inc, off, 64);
            if (t >= off) inc += u;
        }
        int ex = inc - sum;
        if (b0     < NSB) runstart[b0]     = ex;
        if (b0 + 1 < NSB) runstart[b0 + 1] = ex + h0;
        if (b0 + 2 < NSB) runstart[b0 + 2] = ex + s01;
        if (b0 + 3 < NSB) runstart[b0 + 3] = ex + s01 + h2;
    }
    __syncthreads();

    if (t < NSB) {
        int h = hist[t];
        gbase[t] = h ? atomicAdd(&gcursor[t], h) : 0;
        cur[t] = 0;
    }
    __syncthreads();

#pragma unroll
    for (int j = 0; j < EPT; ++j) {
        if (d[j] >= 0) {
            int b = d[j] >> SB_SHIFT;
            int idx = runstart[b] + atomicAdd(&cur[b], 1);
            staged[idx] = ((d[j] & (SB_NODES - 1)) << 17) | s[j];
            sbin[idx] = (unsigned char)b;
        }
    }
    __syncthreads();

    for (int i = t; i < n; i += K1_THREADS) {
        int b = sbin[i];
        int p = staged[i];
        int tgt = gbase[b] + (i - runstart[b]);
        if (tgt < SBCAP) {
            binbuf[b * SBCAP + tgt] = p;
        } else {
            int op = atomicAdd(ovfcnt, 1);
            if (op < OVF_CAP) { ovf[2 * op] = (b << SB_SHIFT) | (p >> 17); ovf[2 * op + 1] = p & 0x1FFFF; }
        }
    }
}

// ============ k23: filter + LDS-atomic output tile, sort-free ============
// One block per 64 nodes. Ballot-compact own entries to klist (order
// irrelevant), then each wave processes 4 keepers per iteration: 4
// independent 256B row loads in flight, ds_add_f32 into the 16KB out tile.
__global__ __launch_bounds__(256) void k23_gather_kernel(
        const float* __restrict__ x, const int* __restrict__ gcursor,
        const int* __restrict__ binbuf, int* __restrict__ ovfcnt,
        int* __restrict__ ovf, float* __restrict__ out) {
    __shared__ __align__(16) float acc[NPB * D_FEAT];  // 16 KB
    __shared__ int klist[KCAP];                        // 5 KB
    __shared__ int nk;

    // bijective XCD swizzle: 8 sibling blocks of a superbin share one XCD L2
    int bid = blockIdx.x;
    int q = NBLK >> 3, r = NBLK & 7;
    int xcd = bid & 7, lid = bid >> 3;
    int blk = (xcd < r ? xcd * (q + 1) : r * (q + 1) + (xcd - r) * q) + lid;

    int t = threadIdx.x;
    int lane = t & 63;
    int w = t >> 6;
#pragma unroll
    for (int j = 0; j < (NPB * D_FEAT / 4) / 256; ++j)
        ((float4*)acc)[t + j * 256] = make_float4(0.f, 0.f, 0.f, 0.f);
    if (t == 0) nk = 0;
    __syncthreads();

    int sb  = blk >> 3;       // parent superbin
    int my3 = blk & 7;        // 64-node window within superbin
    int n = gcursor[sb];
    if (n > SBCAP) n = SBCAP;
    const int* buf = binbuf + (size_t)sb * SBCAP;

    // filter stream: keep entries whose window == my3
    for (int i0 = 0; i0 < n; i0 += 256) {
        int i = i0 + t;
        int p = (i < n) ? buf[i] : -1;
        bool keep = (p >= 0) && (((p >> 23) & 7) == my3);
        unsigned long long m = __ballot(keep);
        int tot = __popcll(m);
        int bpos;
        if (lane == 0) bpos = atomicAdd(&nk, tot);
        bpos = __shfl(bpos, 0, 64);
        if (keep) {
            int pos = bpos + __popcll(m & ((1ull << lane) - 1));
            if (pos < KCAP) {
                klist[pos] = p;
            } else {
                int op = atomicAdd(ovfcnt, 1);
                if (op < OVF_CAP) {
                    ovf[2 * op]     = (sb << SB_SHIFT) | (p >> 17);
                    ovf[2 * op + 1] = p & 0x1FFFF;
                }
            }
        }
    }
    __syncthreads();

    // keeper processing: wave w takes keepers [k0, k0+4), stride 16.
    // 4 independent full-row loads in flight per wave; ds_add_f32 accumulate.
    int kn = nk;
    if (kn > KCAP) kn = KCAP;
    for (int k0 = w * 4; k0 < kn; k0 += 16) {
        int pk0 = klist[k0];
        int pk1 = (k0 + 1 < kn) ? klist[k0 + 1] : -1;
        int pk2 = (k0 + 2 < kn) ? klist[k0 + 2] : -1;
        int pk3 = (k0 + 3 < kn) ? klist[k0 + 3] : -1;
        float v0 = x[(size_t)(pk0 & 0x1FFFF) * D_FEAT + lane];
        float v1 = (pk1 >= 0) ? x[(size_t)(pk1 & 0x1FFFF) * D_FEAT + lane] : 0.f;
        float v2 = (pk2 >= 0) ? x[(size_t)(pk2 & 0x1FFFF) * D_FEAT + lane] : 0.f;
        float v3 = (pk3 >= 0) ? x[(size_t)(pk3 & 0x1FFFF) * D_FEAT + lane] : 0.f;
        atomicAdd(&acc[((pk0 >> 17) & 63) * D_FEAT + lane], v0);
        if (pk1 >= 0) atomicAdd(&acc[((pk1 >> 17) & 63) * D_FEAT + lane], v1);
        if (pk2 >= 0) atomicAdd(&acc[((pk2 >> 17) & 63) * D_FEAT + lane], v2);
        if (pk3 >= 0) atomicAdd(&acc[((pk3 >> 17) & 63) * D_FEAT + lane], v3);
    }
    __syncthreads();

    // coalesced tile writeout: 64 nodes x 16 float4
    int base_node = blk * NPB;
    const float4* a4 = (const float4*)acc;
#pragma unroll
    for (int j = 0; j < 4; ++j) {
        int qq = t + j * 256;
        int dl = qq >> 4, c4 = qq & 15;
        int node = base_node + dl;
        if (node < N_NODES)
            ((float4*)out)[(size_t)node * 16 + c4] = a4[qq];
    }
}

// Add any overflow edges (statistically none) on top of the gathered output.
__global__ __launch_bounds__(256) void ovf_fixup_kernel(
        const float* __restrict__ x, const int* __restrict__ ovfcnt,
        const int* __restrict__ ovf, float* __restrict__ out) {
    int n = *ovfcnt;
    if (n > OVF_CAP) n = OVF_CAP;
    long long total = (long long)n * 16;
    long long stride = (long long)gridDim.x * blockDim.x;
    for (long long t = blockIdx.x * blockDim.x + threadIdx.x; t < total; t += stride) {
        int e  = (int)(t >> 4);
        int fo = ((int)t & 15) << 2;
        int d = ovf[2 * e];
        int s = ovf[2 * e + 1];
        const float4 v = *(const float4*)(x + (size_t)s * D_FEAT + fo);
        float* o = out + (size_t)d * D_FEAT + fo;
        atomicAdd(o + 0, v.x);
        atomicAdd(o + 1, v.y);
        atomicAdd(o + 2, v.z);
        atomicAdd(o + 3, v.w);
    }
}

// ====================== fallback: atomic scatter-add ======================

__global__ __launch_bounds__(256) void zero_f4_kernel(float* __restrict__ out, int n4) {
    int i = blockIdx.x * blockDim.x + threadIdx.x;
    if (i < n4) ((float4*)out)[i] = make_float4(0.f, 0.f, 0.f, 0.f);
}

__global__ __launch_bounds__(256) void scatter_add_kernel(const float* __restrict__ x,
                                                          const int* __restrict__ idxi,
                                                          const int* __restrict__ idxj,
                                                          float* __restrict__ out) {
    int t = blockIdx.x * blockDim.x + threadIdx.x;
    int e = t >> 4;
    if (e >= N_EDGES) return;
    int fo = (t & 15) << 2;
    int dst = idxi[e];
    int src = idxj[e];
    const float4 v = *(const float4*)(x + (size_t)src * D_FEAT + fo);
    float* o = out + (size_t)dst * D_FEAT + fo;
    atomicAdd(o + 0, v.x);
    atomicAdd(o + 1, v.y);
    atomicAdd(o + 2, v.z);
    atomicAdd(o + 3, v.w);
}

extern "C" void kernel_launch(void* const* d_in, const int* in_sizes, int n_in,
                              void* d_out, int out_size, void* d_ws, size_t ws_size,
                              hipStream_t stream) {
    const float* x  = (const float*)d_in[0];
    const int*   ei = (const int*)d_in[1];   // flat (2, N_EDGES)
    const int*   idxi = ei;                  // row 0: destinations
    const int*   idxj = ei + N_EDGES;        // row 1: sources
    float* out = (float*)d_out;

    // --- primary: superbin binning + sort-free LDS-atomic gather ---
    // ws (ints): gcursor[256] | ovfcnt+pad[16] | ovf[2*OVF_CAP] | binbuf[NSB*SBCAP]
    {
        size_t need = (256 + 16 + 2 * (size_t)OVF_CAP +
                       (size_t)NSB * SBCAP) * sizeof(int);
        if (ws_size >= need) {
            int* gcursor = (int*)d_ws;
            int* ovfcnt  = gcursor + 256;
            int* ovf     = ovfcnt + 16;
            int* binbuf  = ovf + 2 * OVF_CAP;

            hipMemsetAsync(gcursor, 0, (256 + 16) * sizeof(int), stream);
            k1_bin_kernel<<<K1B, K1_THREADS, 0, stream>>>(idxi, idxj, gcursor,
                                                          ovfcnt, ovf, binbuf);
            k23_gather_kernel<<<NBLK, 256, 0, stream>>>(x, gcursor, binbuf,
                                                        ovfcnt, ovf, out);
            ovf_fixup_kernel<<<16, 256, 0, stream>>>(x, ovfcnt, ovf, out);
            return;
        }
    }

    // --- fallback: atomic scatter-add ---
    int n4 = (N_NODES * D_FEAT) / 4;
    zero_f4_kernel<<<(n4 + 255) / 256, 256, 0, stream>>>(out, n4);
    long long total_threads = (long long)N_EDGES * 16;
    scatter_add_kernel<<<(int)((total_threads + 255) / 256), 256, 0, stream>>>(x, idxi, idxj, out);
}